// Round 9
// baseline (78.063 us; speedup 1.0000x reference)
//
#include <hip/hip_runtime.h>
#include <hip/hip_bf16.h>
#include <math.h>

#define N_NEUR 2048
#define EMB 1024
#define S_TOT 8192
#define NW 12

typedef __attribute__((ext_vector_type(8))) short bf16x8;
typedef __attribute__((ext_vector_type(4))) float f32x4;

__device__ inline short f2bf(float f) {
    union { float f; unsigned u; } v; v.f = f;
    unsigned r = v.u + 0x7FFFu + ((v.u >> 16) & 1u);   // RNE
    return (short)(r >> 16);
}

// Cast x-tail (rows 6144..8191) and n_weights to bf16; also zero seg.
__global__ __launch_bounds__(256) void precast(const float* __restrict__ xt,
                                               const float* __restrict__ nw,
                                               short* __restrict__ A,
                                               short* __restrict__ W,
                                               float* __restrict__ seg) {
    const int HALF = (N_NEUR * EMB) / 4;   // 524288 float4 groups per matrix
    int g = blockIdx.x * 256 + threadIdx.x;
    if (g < (NW * N_NEUR) / 4) ((float4*)seg)[g] = make_float4(0.f, 0.f, 0.f, 0.f);
    int gg = g;
    const float4* src; short* dst;
    if (gg < HALF) { src = (const float4*)xt; dst = A; }
    else           { gg -= HALF; src = (const float4*)nw; dst = W; }
    float4 v = src[gg];
    short4 o;
    o.x = f2bf(v.x); o.y = f2bf(v.y); o.z = f2bf(v.z); o.w = f2bf(v.w);
    *(short4*)(dst + (size_t)gg * 4) = o;
}

// Fused GEMM + tanh + segment-sum.  64x64 tile, BK=64, 4 waves (2x2 of 32x32),
// 1024 blocks = 4/CU (R7 proven TLP).  A: global_load_lds staging, dbuf LDS,
// XOR slot-swizzle both-sides (r21).  B: NOT staged in LDS — each wave loads
// its MFMA B-fragments directly from global (L2-resident panels) into named
// even/odd register sets (rule #20: no runtime-indexed reg arrays).  This
// halves LDS traffic (48->24 KB per block-step), the R7 bottleneck.
// NOTE (R6 lesson): NO cross-block fusion / __threadfence here.
#define GLDS(g, l) __builtin_amdgcn_global_load_lds(                          \
    (const __attribute__((address_space(1))) void*)(g),                       \
    (__attribute__((address_space(3))) void*)(l), 16, 0, 0)

__global__ __launch_bounds__(256, 4) void gemm_seg(const short* __restrict__ A,
                                                   const short* __restrict__ W,
                                                   const float* __restrict__ bias,
                                                   float* __restrict__ seg) {
    __shared__ short As[2][64 * 64];
    const int t = threadIdx.x;
    const int bm = blockIdx.y, bn = blockIdx.x;
    const int lane = t & 63, wid = t >> 6;
    const int wr = wid >> 1, wc = wid & 1;
    const int l15 = lane & 15, lhi = lane >> 4;
    const int srow = lane >> 3;            // 0..7 within 8-row issue
    const int pslot = (lane & 7) ^ srow;   // pre-swizzled source slot
    const short* gA0 = A + (size_t)(bm * 64 + wid * 16 + 0 + srow) * EMB + pslot * 8;
    const short* gA1 = A + (size_t)(bm * 64 + wid * 16 + 8 + srow) * EMB + pslot * 8;
    short* lA0[2] = { &As[0][(wid * 16 + 0) * 64], &As[1][(wid * 16 + 0) * 64] };
    short* lA1[2] = { &As[0][(wid * 16 + 8) * 64], &As[1][(wid * 16 + 8) * 64] };
    // B fragment pointers: row = bn*64 + wc*32 + n*16 + l15, k = k0 + kk*32 + lhi*8
    const short* gBn0 = W + (size_t)(bn * 64 + wc * 32 + 0 * 16 + l15) * EMB + lhi * 8;
    const short* gBn1 = W + (size_t)(bn * 64 + wc * 32 + 1 * 16 + l15) * EMB + lhi * 8;

    f32x4 acc[2][2] = {};

#define LOADB(dst, k0) do {                                                   \
    dst[0][0] = *(const bf16x8*)(gBn0 + (k0));                                \
    dst[1][0] = *(const bf16x8*)(gBn0 + (k0) + 32);                           \
    dst[0][1] = *(const bf16x8*)(gBn1 + (k0));                                \
    dst[1][1] = *(const bf16x8*)(gBn1 + (k0) + 32);                           \
    } while (0)

#define READA(buf)                                                            \
    bf16x8 af[2][2];                                                          \
    _Pragma("unroll")                                                         \
    for (int kk = 0; kk < 2; ++kk)                                            \
        _Pragma("unroll")                                                     \
        for (int m = 0; m < 2; ++m) {                                         \
            int row = wr * 32 + m * 16 + l15;                                 \
            int slot = (kk * 4 + lhi) ^ (row & 7);                            \
            af[kk][m] = *(const bf16x8*)&As[buf][row * 64 + slot * 8];        \
        }

#define DOMFMA(bsrc) do {                                                     \
    __builtin_amdgcn_s_setprio(1);                                            \
    _Pragma("unroll")                                                         \
    for (int kk = 0; kk < 2; ++kk)                                            \
        _Pragma("unroll")                                                     \
        for (int m = 0; m < 2; ++m)                                           \
            _Pragma("unroll")                                                 \
            for (int n = 0; n < 2; ++n)                                       \
                acc[m][n] = __builtin_amdgcn_mfma_f32_16x16x32_bf16(          \
                    af[kk][m], bsrc[kk][n], acc[m][n], 0, 0, 0);              \
    __builtin_amdgcn_s_setprio(0);                                            \
    } while (0)

    bf16x8 bregE[2][2], bregO[2][2];      // named even/odd B double-buffer

    // prologue: tile 0
    GLDS(gA0, lA0[0]); GLDS(gA1, lA1[0]);
    LOADB(bregE, 0);
    __syncthreads();

    #pragma unroll 1
    for (int kp = 0; kp < 8; ++kp) {
        // even phase: compute tile 2kp from As[0]/bregE, prefetch tile 2kp+1
        {
            int k0n = (2 * kp + 1) * 64;
            GLDS(gA0 + k0n, lA0[1]); GLDS(gA1 + k0n, lA1[1]);
            LOADB(bregO, k0n);
            READA(0);
            DOMFMA(bregE);
            __syncthreads();
        }
        // odd phase: compute tile 2kp+1 from As[1]/bregO, prefetch tile 2kp+2
        {
            if (kp < 7) {
                int k0n = (2 * kp + 2) * 64;
                GLDS(gA0 + k0n, lA0[0]); GLDS(gA1 + k0n, lA1[0]);
                LOADB(bregE, k0n);
            }
            READA(1);
            DOMFMA(bregO);
            __syncthreads();
        }
    }

    // Epilogue. C/D layout: col = lane&15, row(within frag) = lhi*4 + j.
    if (bm > 0) {
        int jseg = 38 - __clz(bm);   // floor(log2(bm*64)) + 1
        #pragma unroll
        for (int n = 0; n < 2; ++n) {
            int col = bn * 64 + wc * 32 + n * 16 + l15;
            float bc = bias[col];
            float s = 0.f;
            #pragma unroll
            for (int m = 0; m < 2; ++m)
                #pragma unroll
                for (int j = 0; j < 4; ++j)
                    s += tanhf(acc[m][n][j] + bc);
            s += __shfl_xor(s, 16);
            s += __shfl_xor(s, 32);
            if (lhi == 0) atomicAdd(&seg[jseg * N_NEUR + col], s);
        }
    } else {
        #pragma unroll
        for (int n = 0; n < 2; ++n) {
            int col = bn * 64 + wc * 32 + n * 16 + l15;
            float bc = bias[col];
            if (wr == 1) {                 // rows 32..63 -> seg 6
                float s = 0.f;
                #pragma unroll
                for (int m = 0; m < 2; ++m)
                    #pragma unroll
                    for (int j = 0; j < 4; ++j)
                        s += tanhf(acc[m][n][j] + bc);
                s += __shfl_xor(s, 16);
                s += __shfl_xor(s, 32);
                if (lhi == 0) atomicAdd(&seg[6 * N_NEUR + col], s);
            } else {
                float s = 0.f;             // rows 16..31 -> seg 5
                #pragma unroll
                for (int j = 0; j < 4; ++j)
                    s += tanhf(acc[1][n][j] + bc);
                s += __shfl_xor(s, 16);
                s += __shfl_xor(s, 32);
                if (lhi == 0) atomicAdd(&seg[5 * N_NEUR + col], s);
                #pragma unroll
                for (int j = 0; j < 4; ++j) {  // rows 0..15 per-row segments
                    int r = lhi * 4 + j;
                    int sj = (r == 0) ? 0 : (32 - __clz(r));
                    atomicAdd(&seg[sj * N_NEUR + col], tanhf(acc[0][n][j] + bc));
                }
            }
        }
    }
}

// wout[w][n] = prefix(seg)/2^w  AND  out[n] = (61/60)*sum_w cb[w][n] + 1.
__global__ __launch_bounds__(256) void winout_init(const float* __restrict__ seg,
                                                   const float* __restrict__ cb,
                                                   float* __restrict__ wout,
                                                   float* __restrict__ out) {
    int n = blockIdx.x * 256 + threadIdx.x;
    float run = 0.f;
    #pragma unroll
    for (int w = 0; w < NW; ++w) {
        run += seg[w * N_NEUR + n];
        wout[w * N_NEUR + n] = run * (1.0f / (float)(1 << w));
    }
    float bs = 0.f;
    #pragma unroll
    for (int w = 0; w < NW; ++w) bs += cb[w * N_NEUR + n];
    out[n] = 1.0166666666666666f * bs + 1.0f;
}

// out[m] += (61/60) * dot(combo_w[w][m][:], wout[w][:]) ; one wave per (w,m).
__global__ __launch_bounds__(256) void combo_dot(const float* __restrict__ cw,
                                                 const float* __restrict__ wout,
                                                 float* __restrict__ out) {
    int wid = threadIdx.x >> 6, lane = threadIdx.x & 63;
    int r = blockIdx.x * 4 + wid;             // 0..24575
    int w = r >> 11, m = r & 2047;
    const float4* row  = (const float4*)(cw + (size_t)(w * N_NEUR + m) * N_NEUR);
    const float4* wrow = (const float4*)(wout + w * N_NEUR);
    float s = 0.f;
    #pragma unroll
    for (int i = 0; i < 8; ++i) {
        float4 a = row[i * 64 + lane];
        float4 b = wrow[i * 64 + lane];
        s += a.x * b.x + a.y * b.y + a.z * b.z + a.w * b.w;
    }
    #pragma unroll
    for (int off = 32; off > 0; off >>= 1) s += __shfl_down(s, off);
    if (lane == 0) atomicAdd(&out[m], 1.0166666666666666f * s);
}

extern "C" void kernel_launch(void* const* d_in, const int* in_sizes, int n_in,
                              void* d_out, int out_size, void* d_ws, size_t ws_size,
                              hipStream_t stream) {
    const float* x  = (const float*)d_in[0];
    const float* nw = (const float*)d_in[1];
    const float* nb = (const float*)d_in[2];
    const float* cw = (const float*)d_in[3];
    const float* cb = (const float*)d_in[4];
    float* out = (float*)d_out;

    char* ws = (char*)d_ws;
    float* seg  = (float*)ws;                              // 12*2048 f32   (96 KB)
    float* wout = (float*)(ws + 98304);                    // 12*2048 f32   (96 KB)
    short* Abf  = (short*)(ws + 204800);                   // 2048*1024 bf16 (4 MB)
    short* Wbf  = (short*)(ws + 204800 + 4194304);         // 2048*1024 bf16 (4 MB)

    precast<<<4096, 256, 0, stream>>>(x + (size_t)(S_TOT - 2048) * EMB, nw, Abf, Wbf, seg);

    dim3 g1(32, 32);
    gemm_seg<<<g1, 256, 0, stream>>>(Abf, Wbf, nb, seg);

    winout_init<<<8, 256, 0, stream>>>(seg, cb, wout, out);

    combo_dot<<<6144, 256, 0, stream>>>(cw, wout, out);
}

// Round 10
// 75.866 us; speedup vs baseline: 1.0290x; 1.0290x over previous
//
#include <hip/hip_runtime.h>
#include <hip/hip_bf16.h>
#include <math.h>

#define N_NEUR 2048
#define EMB 1024
#define S_TOT 8192
#define NW 12

typedef __attribute__((ext_vector_type(8))) short bf16x8;
typedef __attribute__((ext_vector_type(4))) float f32x4;

__device__ inline short f2bf(float f) {
    union { float f; unsigned u; } v; v.f = f;
    unsigned r = v.u + 0x7FFFu + ((v.u >> 16) & 1u);   // RNE
    return (short)(r >> 16);
}

// Cast x-tail (rows 6144..8191) and n_weights to bf16; zero seg; init out.
__global__ __launch_bounds__(256) void precast(const float* __restrict__ xt,
                                               const float* __restrict__ nw,
                                               const float* __restrict__ cb,
                                               short* __restrict__ A,
                                               short* __restrict__ W,
                                               float* __restrict__ seg,
                                               float* __restrict__ out) {
    const int HALF = (N_NEUR * EMB) / 4;   // 524288 float4 groups per matrix
    int g = blockIdx.x * 256 + threadIdx.x;
    if (g < (NW * N_NEUR) / 4) ((float4*)seg)[g] = make_float4(0.f, 0.f, 0.f, 0.f);
    if (g < N_NEUR / 4) {                  // out[n] = (61/60)*sum_w cb[w][n] + 1
        const float4* cb4 = (const float4*)cb;
        float4 s = make_float4(0.f, 0.f, 0.f, 0.f);
        #pragma unroll
        for (int w = 0; w < NW; ++w) {
            float4 c = cb4[w * (N_NEUR / 4) + g];
            s.x += c.x; s.y += c.y; s.z += c.z; s.w += c.w;
        }
        float4 o;
        o.x = 1.0166666666666666f * s.x + 1.0f;
        o.y = 1.0166666666666666f * s.y + 1.0f;
        o.z = 1.0166666666666666f * s.z + 1.0f;
        o.w = 1.0166666666666666f * s.w + 1.0f;
        ((float4*)out)[g] = o;
    }
    int gg = g;
    const float4* src; short* dst;
    if (gg < HALF) { src = (const float4*)xt; dst = A; }
    else           { gg -= HALF; src = (const float4*)nw; dst = W; }
    float4 v = src[gg];
    short4 o;
    o.x = f2bf(v.x); o.y = f2bf(v.y); o.z = f2bf(v.z); o.w = f2bf(v.w);
    *(short4*)(dst + (size_t)gg * 4) = o;
}

// Fused GEMM + tanh + segment-sum.  64x64 tile, BK=64, 4 waves (2x2 of 32x32),
// 1024 blocks = 4/CU.  R7-proven structure: global_load_lds(16B) staging,
// double-buffered LDS, one __syncthreads per K-step, XOR slot-swizzle on BOTH
// global source and ds_read (r21).  Do NOT modify (R8/R9 both regressed).
#define GLDS(g, l) __builtin_amdgcn_global_load_lds(                          \
    (const __attribute__((address_space(1))) void*)(g),                       \
    (__attribute__((address_space(3))) void*)(l), 16, 0, 0)

__global__ __launch_bounds__(256) void gemm_seg(const short* __restrict__ A,
                                                const short* __restrict__ W,
                                                const float* __restrict__ bias,
                                                float* __restrict__ seg) {
    __shared__ short As[2][64 * 64];
    __shared__ short Bs[2][64 * 64];
    const int t = threadIdx.x;
    const int bm = blockIdx.y, bn = blockIdx.x;
    const int lane = t & 63, wid = t >> 6;
    const int wr = wid >> 1, wc = wid & 1;
    const int l15 = lane & 15, lhi = lane >> 4;
    const int srow = lane >> 3;            // 0..7 within 8-row issue
    const int pslot = (lane & 7) ^ srow;   // pre-swizzled source slot
    const short* gA0 = A + (size_t)(bm * 64 + wid * 16 + 0 + srow) * EMB + pslot * 8;
    const short* gA1 = A + (size_t)(bm * 64 + wid * 16 + 8 + srow) * EMB + pslot * 8;
    const short* gB0 = W + (size_t)(bn * 64 + wid * 16 + 0 + srow) * EMB + pslot * 8;
    const short* gB1 = W + (size_t)(bn * 64 + wid * 16 + 8 + srow) * EMB + pslot * 8;
    short* lA0[2] = { &As[0][(wid * 16 + 0) * 64], &As[1][(wid * 16 + 0) * 64] };
    short* lA1[2] = { &As[0][(wid * 16 + 8) * 64], &As[1][(wid * 16 + 8) * 64] };
    short* lB0[2] = { &Bs[0][(wid * 16 + 0) * 64], &Bs[1][(wid * 16 + 0) * 64] };
    short* lB1[2] = { &Bs[0][(wid * 16 + 8) * 64], &Bs[1][(wid * 16 + 8) * 64] };

    f32x4 acc[2][2] = {};

    GLDS(gA0, lA0[0]); GLDS(gA1, lA1[0]);
    GLDS(gB0, lB0[0]); GLDS(gB1, lB1[0]);
    __syncthreads();

    int cur = 0;
    for (int ks = 0; ks < 16; ++ks) {
        if (ks < 15) {
            int k0 = (ks + 1) * 64;
            GLDS(gA0 + k0, lA0[cur ^ 1]); GLDS(gA1 + k0, lA1[cur ^ 1]);
            GLDS(gB0 + k0, lB0[cur ^ 1]); GLDS(gB1 + k0, lB1[cur ^ 1]);
        }
        bf16x8 af[2][2], bb[2][2];
        #pragma unroll
        for (int kk = 0; kk < 2; ++kk) {
            #pragma unroll
            for (int m = 0; m < 2; ++m) {
                int row = wr * 32 + m * 16 + l15;
                int slot = (kk * 4 + lhi) ^ (row & 7);
                af[kk][m] = *(const bf16x8*)&As[cur][row * 64 + slot * 8];
            }
            #pragma unroll
            for (int n = 0; n < 2; ++n) {
                int row = wc * 32 + n * 16 + l15;
                int slot = (kk * 4 + lhi) ^ (row & 7);
                bb[kk][n] = *(const bf16x8*)&Bs[cur][row * 64 + slot * 8];
            }
        }
        __builtin_amdgcn_s_setprio(1);
        #pragma unroll
        for (int kk = 0; kk < 2; ++kk)
            #pragma unroll
            for (int m = 0; m < 2; ++m)
                #pragma unroll
                for (int n = 0; n < 2; ++n)
                    acc[m][n] = __builtin_amdgcn_mfma_f32_16x16x32_bf16(af[kk][m], bb[kk][n], acc[m][n], 0, 0, 0);
        __builtin_amdgcn_s_setprio(0);
        __syncthreads();
        cur ^= 1;
    }

    // Epilogue. C/D layout: col = lane&15, row(within frag) = lhi*4 + j.
    if (bm > 0) {
        int jseg = 38 - __clz(bm);   // floor(log2(bm*64)) + 1
        #pragma unroll
        for (int n = 0; n < 2; ++n) {
            int col = bn * 64 + wc * 32 + n * 16 + l15;
            float bc = bias[col];
            float s = 0.f;
            #pragma unroll
            for (int m = 0; m < 2; ++m)
                #pragma unroll
                for (int j = 0; j < 4; ++j)
                    s += tanhf(acc[m][n][j] + bc);
            s += __shfl_xor(s, 16);
            s += __shfl_xor(s, 32);
            if (lhi == 0) atomicAdd(&seg[jseg * N_NEUR + col], s);
        }
    } else {
        #pragma unroll
        for (int n = 0; n < 2; ++n) {
            int col = bn * 64 + wc * 32 + n * 16 + l15;
            float bc = bias[col];
            if (wr == 1) {                 // rows 32..63 -> seg 6
                float s = 0.f;
                #pragma unroll
                for (int m = 0; m < 2; ++m)
                    #pragma unroll
                    for (int j = 0; j < 4; ++j)
                        s += tanhf(acc[m][n][j] + bc);
                s += __shfl_xor(s, 16);
                s += __shfl_xor(s, 32);
                if (lhi == 0) atomicAdd(&seg[6 * N_NEUR + col], s);
            } else {
                float s = 0.f;             // rows 16..31 -> seg 5
                #pragma unroll
                for (int j = 0; j < 4; ++j)
                    s += tanhf(acc[1][n][j] + bc);
                s += __shfl_xor(s, 16);
                s += __shfl_xor(s, 32);
                if (lhi == 0) atomicAdd(&seg[5 * N_NEUR + col], s);
                #pragma unroll
                for (int j = 0; j < 4; ++j) {  // rows 0..15 per-row segments
                    int r = lhi * 4 + j;
                    int sj = (r == 0) ? 0 : (32 - __clz(r));
                    atomicAdd(&seg[sj * N_NEUR + col], tanhf(acc[0][n][j] + bc));
                }
            }
        }
    }
}

// Per block: one window w (4 rows m).  Build wout[w][:] into LDS from seg
// (prefix over rows 0..w, / 2^w), then out[m] += (61/60)*dot(cw[w][m], wrow).
__global__ __launch_bounds__(256) void combo_dot(const float* __restrict__ cw,
                                                 const float* __restrict__ seg,
                                                 float* __restrict__ out) {
    __shared__ float wrow[N_NEUR];
    const int t = threadIdx.x;
    const int r0 = blockIdx.x * 4;            // first of 4 rows, all same w
    const int w = r0 >> 11;
    const float inv = 1.0f / (float)(1 << w);
    // build wrow: thread t handles n = t, t+256, ... (coalesced)
    for (int n = t; n < N_NEUR; n += 256) {
        float s = 0.f;
        for (int j = 0; j <= w; ++j) s += seg[j * N_NEUR + n];
        wrow[n] = s * inv;
    }
    __syncthreads();
    const int wid = t >> 6, lane = t & 63;
    const int m = (r0 + wid) & 2047;
    const float4* row = (const float4*)(cw + (size_t)(w * N_NEUR + m) * N_NEUR);
    const float4* wr4 = (const float4*)wrow;
    float s = 0.f;
    #pragma unroll
    for (int i = 0; i < 8; ++i) {
        float4 a = row[i * 64 + lane];
        float4 b = wr4[i * 64 + lane];
        s += a.x * b.x + a.y * b.y + a.z * b.z + a.w * b.w;
    }
    #pragma unroll
    for (int off = 32; off > 0; off >>= 1) s += __shfl_down(s, off);
    if (lane == 0) atomicAdd(&out[m], 1.0166666666666666f * s);
}

extern "C" void kernel_launch(void* const* d_in, const int* in_sizes, int n_in,
                              void* d_out, int out_size, void* d_ws, size_t ws_size,
                              hipStream_t stream) {
    const float* x  = (const float*)d_in[0];
    const float* nw = (const float*)d_in[1];
    const float* nb = (const float*)d_in[2];
    const float* cw = (const float*)d_in[3];
    const float* cb = (const float*)d_in[4];
    float* out = (float*)d_out;

    char* ws = (char*)d_ws;
    float* seg  = (float*)ws;                              // 12*2048 f32   (96 KB)
    short* Abf  = (short*)(ws + 204800);                   // 2048*1024 bf16 (4 MB)
    short* Wbf  = (short*)(ws + 204800 + 4194304);         // 2048*1024 bf16 (4 MB)

    precast<<<4096, 256, 0, stream>>>(x + (size_t)(S_TOT - 2048) * EMB, nw, cb,
                                      Abf, Wbf, seg, out);

    dim3 g1(32, 32);
    gemm_seg<<<g1, 256, 0, stream>>>(Abf, Wbf, nb, seg);

    combo_dot<<<6144, 256, 0, stream>>>(cw, seg, out);
}

// Round 11
// 56.679 us; speedup vs baseline: 1.3773x; 1.3385x over previous
//
#include <hip/hip_runtime.h>
#include <hip/hip_bf16.h>
#include <math.h>

#define N_NEUR 2048
#define EMB 1024
#define S_TOT 8192
#define NW 12

typedef __attribute__((ext_vector_type(8))) short bf16x8;
typedef __attribute__((ext_vector_type(4))) float f32x4;

__device__ inline short f2bf(float f) {
    union { float f; unsigned u; } v; v.f = f;
    unsigned r = v.u + 0x7FFFu + ((v.u >> 16) & 1u);   // RNE
    return (short)(r >> 16);
}

// Cast x-tail (rows 6144..8191) and n_weights to bf16; zero seg; init out.
__global__ __launch_bounds__(256) void precast(const float* __restrict__ xt,
                                               const float* __restrict__ nw,
                                               const float* __restrict__ cb,
                                               short* __restrict__ A,
                                               short* __restrict__ W,
                                               float* __restrict__ seg,
                                               float* __restrict__ out) {
    const int HALF = (N_NEUR * EMB) / 4;   // 524288 float4 groups per matrix
    int g = blockIdx.x * 256 + threadIdx.x;
    if (g < (NW * N_NEUR) / 4) ((float4*)seg)[g] = make_float4(0.f, 0.f, 0.f, 0.f);
    if (g < N_NEUR / 4) {                  // out[n] = (61/60)*sum_w cb[w][n] + 1
        const float4* cb4 = (const float4*)cb;
        float4 s = make_float4(0.f, 0.f, 0.f, 0.f);
        #pragma unroll
        for (int w = 0; w < NW; ++w) {
            float4 c = cb4[w * (N_NEUR / 4) + g];
            s.x += c.x; s.y += c.y; s.z += c.z; s.w += c.w;
        }
        float4 o;
        o.x = 1.0166666666666666f * s.x + 1.0f;
        o.y = 1.0166666666666666f * s.y + 1.0f;
        o.z = 1.0166666666666666f * s.z + 1.0f;
        o.w = 1.0166666666666666f * s.w + 1.0f;
        ((float4*)out)[g] = o;
    }
    int gg = g;
    const float4* src; short* dst;
    if (gg < HALF) { src = (const float4*)xt; dst = A; }
    else           { gg -= HALF; src = (const float4*)nw; dst = W; }
    float4 v = src[gg];
    short4 o;
    o.x = f2bf(v.x); o.y = f2bf(v.y); o.z = f2bf(v.z); o.w = f2bf(v.w);
    *(short4*)(dst + (size_t)gg * 4) = o;
}

// Fused GEMM + tanh + segment-sum.  64x64 tile, BK=64, 4 waves (2x2 of 32x32),
// 1024 blocks = 4/CU.  R7-proven loop structure: global_load_lds(16B) staging,
// double-buffered LDS, one __syncthreads per K-step, XOR slot-swizzle on BOTH
// global source and ds_read (r21).  ONLY change vs R7: 2D XCD-chunk block
// swizzle (each XCD owns a 16x8 bm,bn rect -> 3 MB working set < 4 MB L2).
// NOTE: no cross-block fusion / __threadfence (R6); no vmcnt 3-buf (R8);
// no B-from-global (R9); no wout fold into combo (R10).
#define GLDS(g, l) __builtin_amdgcn_global_load_lds(                          \
    (const __attribute__((address_space(1))) void*)(g),                       \
    (__attribute__((address_space(3))) void*)(l), 16, 0, 0)

__global__ __launch_bounds__(256) void gemm_seg(const short* __restrict__ A,
                                                const short* __restrict__ W,
                                                const float* __restrict__ bias,
                                                float* __restrict__ seg) {
    __shared__ short As[2][64 * 64];
    __shared__ short Bs[2][64 * 64];
    const int t = threadIdx.x;
    // XCD-chunk swizzle: 1024 blocks, 8 XCDs, each a 16x8 (bm,bn) rect.
    const int wgid = blockIdx.x;
    const int xcd = wgid & 7, local = wgid >> 3;
    const int bm = (xcd >> 2) * 16 + (local >> 3);   // 0..31
    const int bn = (xcd & 3) * 8 + (local & 7);      // 0..31
    const int lane = t & 63, wid = t >> 6;
    const int wr = wid >> 1, wc = wid & 1;
    const int l15 = lane & 15, lhi = lane >> 4;
    const int srow = lane >> 3;            // 0..7 within 8-row issue
    const int pslot = (lane & 7) ^ srow;   // pre-swizzled source slot
    const short* gA0 = A + (size_t)(bm * 64 + wid * 16 + 0 + srow) * EMB + pslot * 8;
    const short* gA1 = A + (size_t)(bm * 64 + wid * 16 + 8 + srow) * EMB + pslot * 8;
    const short* gB0 = W + (size_t)(bn * 64 + wid * 16 + 0 + srow) * EMB + pslot * 8;
    const short* gB1 = W + (size_t)(bn * 64 + wid * 16 + 8 + srow) * EMB + pslot * 8;
    short* lA0[2] = { &As[0][(wid * 16 + 0) * 64], &As[1][(wid * 16 + 0) * 64] };
    short* lA1[2] = { &As[0][(wid * 16 + 8) * 64], &As[1][(wid * 16 + 8) * 64] };
    short* lB0[2] = { &Bs[0][(wid * 16 + 0) * 64], &Bs[1][(wid * 16 + 0) * 64] };
    short* lB1[2] = { &Bs[0][(wid * 16 + 8) * 64], &Bs[1][(wid * 16 + 8) * 64] };

    f32x4 acc[2][2] = {};

    GLDS(gA0, lA0[0]); GLDS(gA1, lA1[0]);
    GLDS(gB0, lB0[0]); GLDS(gB1, lB1[0]);
    __syncthreads();

    int cur = 0;
    for (int ks = 0; ks < 16; ++ks) {
        if (ks < 15) {
            int k0 = (ks + 1) * 64;
            GLDS(gA0 + k0, lA0[cur ^ 1]); GLDS(gA1 + k0, lA1[cur ^ 1]);
            GLDS(gB0 + k0, lB0[cur ^ 1]); GLDS(gB1 + k0, lB1[cur ^ 1]);
        }
        bf16x8 af[2][2], bb[2][2];
        #pragma unroll
        for (int kk = 0; kk < 2; ++kk) {
            #pragma unroll
            for (int m = 0; m < 2; ++m) {
                int row = wr * 32 + m * 16 + l15;
                int slot = (kk * 4 + lhi) ^ (row & 7);
                af[kk][m] = *(const bf16x8*)&As[cur][row * 64 + slot * 8];
            }
            #pragma unroll
            for (int n = 0; n < 2; ++n) {
                int row = wc * 32 + n * 16 + l15;
                int slot = (kk * 4 + lhi) ^ (row & 7);
                bb[kk][n] = *(const bf16x8*)&Bs[cur][row * 64 + slot * 8];
            }
        }
        __builtin_amdgcn_s_setprio(1);
        #pragma unroll
        for (int kk = 0; kk < 2; ++kk)
            #pragma unroll
            for (int m = 0; m < 2; ++m)
                #pragma unroll
                for (int n = 0; n < 2; ++n)
                    acc[m][n] = __builtin_amdgcn_mfma_f32_16x16x32_bf16(af[kk][m], bb[kk][n], acc[m][n], 0, 0, 0);
        __builtin_amdgcn_s_setprio(0);
        __syncthreads();
        cur ^= 1;
    }

    // Epilogue. C/D layout: col = lane&15, row(within frag) = lhi*4 + j.
    if (bm > 0) {
        int jseg = 38 - __clz(bm);   // floor(log2(bm*64)) + 1
        #pragma unroll
        for (int n = 0; n < 2; ++n) {
            int col = bn * 64 + wc * 32 + n * 16 + l15;
            float bc = bias[col];
            float s = 0.f;
            #pragma unroll
            for (int m = 0; m < 2; ++m)
                #pragma unroll
                for (int j = 0; j < 4; ++j)
                    s += tanhf(acc[m][n][j] + bc);
            s += __shfl_xor(s, 16);
            s += __shfl_xor(s, 32);
            if (lhi == 0) atomicAdd(&seg[jseg * N_NEUR + col], s);
        }
    } else {
        #pragma unroll
        for (int n = 0; n < 2; ++n) {
            int col = bn * 64 + wc * 32 + n * 16 + l15;
            float bc = bias[col];
            if (wr == 1) {                 // rows 32..63 -> seg 6
                float s = 0.f;
                #pragma unroll
                for (int m = 0; m < 2; ++m)
                    #pragma unroll
                    for (int j = 0; j < 4; ++j)
                        s += tanhf(acc[m][n][j] + bc);
                s += __shfl_xor(s, 16);
                s += __shfl_xor(s, 32);
                if (lhi == 0) atomicAdd(&seg[6 * N_NEUR + col], s);
            } else {
                float s = 0.f;             // rows 16..31 -> seg 5
                #pragma unroll
                for (int j = 0; j < 4; ++j)
                    s += tanhf(acc[1][n][j] + bc);
                s += __shfl_xor(s, 16);
                s += __shfl_xor(s, 32);
                if (lhi == 0) atomicAdd(&seg[5 * N_NEUR + col], s);
                #pragma unroll
                for (int j = 0; j < 4; ++j) {  // rows 0..15 per-row segments
                    int r = lhi * 4 + j;
                    int sj = (r == 0) ? 0 : (32 - __clz(r));
                    atomicAdd(&seg[sj * N_NEUR + col], tanhf(acc[0][n][j] + bc));
                }
            }
        }
    }
}

// wout[w][n] = prefix(seg)/2^w  (out is initialized by precast).
__global__ __launch_bounds__(256) void winout(const float* __restrict__ seg,
                                              float* __restrict__ wout) {
    int n = blockIdx.x * 256 + threadIdx.x;
    float run = 0.f;
    #pragma unroll
    for (int w = 0; w < NW; ++w) {
        run += seg[w * N_NEUR + n];
        wout[w * N_NEUR + n] = run * (1.0f / (float)(1 << w));
    }
}

// out[m] += (61/60) * dot(combo_w[w][m][:], wout[w][:]) ; one wave per (w,m).
__global__ __launch_bounds__(256) void combo_dot(const float* __restrict__ cw,
                                                 const float* __restrict__ wout,
                                                 float* __restrict__ out) {
    int wid = threadIdx.x >> 6, lane = threadIdx.x & 63;
    int r = blockIdx.x * 4 + wid;             // 0..24575
    int w = r >> 11, m = r & 2047;
    const float4* row  = (const float4*)(cw + (size_t)(w * N_NEUR + m) * N_NEUR);
    const float4* wrow = (const float4*)(wout + w * N_NEUR);
    float s = 0.f;
    #pragma unroll
    for (int i = 0; i < 8; ++i) {
        float4 a = row[i * 64 + lane];
        float4 b = wrow[i * 64 + lane];
        s += a.x * b.x + a.y * b.y + a.z * b.z + a.w * b.w;
    }
    #pragma unroll
    for (int off = 32; off > 0; off >>= 1) s += __shfl_down(s, off);
    if (lane == 0) atomicAdd(&out[m], 1.0166666666666666f * s);
}

extern "C" void kernel_launch(void* const* d_in, const int* in_sizes, int n_in,
                              void* d_out, int out_size, void* d_ws, size_t ws_size,
                              hipStream_t stream) {
    const float* x  = (const float*)d_in[0];
    const float* nw = (const float*)d_in[1];
    const float* nb = (const float*)d_in[2];
    const float* cw = (const float*)d_in[3];
    const float* cb = (const float*)d_in[4];
    float* out = (float*)d_out;

    char* ws = (char*)d_ws;
    float* seg  = (float*)ws;                              // 12*2048 f32   (96 KB)
    float* wout = (float*)(ws + 98304);                    // 12*2048 f32   (96 KB)
    short* Abf  = (short*)(ws + 204800);                   // 2048*1024 bf16 (4 MB)
    short* Wbf  = (short*)(ws + 204800 + 4194304);         // 2048*1024 bf16 (4 MB)

    precast<<<4096, 256, 0, stream>>>(x + (size_t)(S_TOT - 2048) * EMB, nw, cb,
                                      Abf, Wbf, seg, out);

    gemm_seg<<<1024, 256, 0, stream>>>(Abf, Wbf, nb, seg);

    winout<<<8, 256, 0, stream>>>(seg, wout);

    combo_dot<<<6144, 256, 0, stream>>>(cw, wout, out);
}